// Round 3
// baseline (582.408 us; speedup 1.0000x reference)
//
#include <hip/hip_runtime.h>

// B=2, C=512, GROUPS=32, H=W=64, N=4096. All heavy math bf16 MFMA.
// ws: ht[8192][512]@0 | QKt[8192][1024]@8M | Vg[512][8192]@24M | AOt[8192][512]@32M
//     Wqk@40M Wv@41M Wo@41.5M Bqk@42M stats@42M+4K ml@42.5M Opart(bf16 2x8192x512)@43M

typedef __attribute__((ext_vector_type(8))) short bf16x8;
typedef __attribute__((ext_vector_type(4))) float f32x4;
typedef unsigned short u16;
typedef unsigned int u32;

__device__ __forceinline__ u16 f2bf(float f) {
  u32 u = __builtin_bit_cast(u32, f);
  return (u16)((u + 0x7FFFu + ((u >> 16) & 1u)) >> 16);
}
__device__ __forceinline__ float bf2f(u16 u) {
  return __builtin_bit_cast(float, (u32)u << 16);
}
__device__ __forceinline__ void gll16(const void* g, void* l) {
  __builtin_amdgcn_global_load_lds((const __attribute__((address_space(1))) u32*)g,
                                   (__attribute__((address_space(3))) u32*)l, 16, 0, 0);
}

// ---------------- GroupNorm: stats (atomic partial) + apply ----------------
__global__ void zero_stats(float* __restrict__ stats) {
  if (threadIdx.x < 128) stats[threadIdx.x] = 0.f;
}

__global__ __launch_bounds__(256) void gn_stats(const float* __restrict__ x,
                                                float* __restrict__ stats) {
  int bg = blockIdx.x >> 3, slice = blockIdx.x & 7;
  const float4* xp = (const float4*)(x + (size_t)bg * 65536 + slice * 8192);
  int t = threadIdx.x;
  float s = 0.f, ss = 0.f;
  for (int i = t; i < 2048; i += 256) {
    float4 v = xp[i];
    s += v.x + v.y + v.z + v.w;
    ss += v.x * v.x + v.y * v.y + v.z * v.z + v.w * v.w;
  }
  for (int off = 32; off > 0; off >>= 1) {
    s += __shfl_down(s, off);
    ss += __shfl_down(ss, off);
  }
  __shared__ float rs[4], rss[4];
  if ((t & 63) == 0) { rs[t >> 6] = s; rss[t >> 6] = ss; }
  __syncthreads();
  if (t == 0) {
    atomicAdd(&stats[bg * 2 + 0], rs[0] + rs[1] + rs[2] + rs[3]);
    atomicAdd(&stats[bg * 2 + 1], rss[0] + rss[1] + rss[2] + rss[3]);
  }
}

__global__ __launch_bounds__(256) void gn_apply(
    const float* __restrict__ x, const float* __restrict__ w,
    const float* __restrict__ b, const float* __restrict__ stats,
    u16* __restrict__ ht) {
  int bg = blockIdx.x >> 3, slice = blockIdx.x & 7;
  int batch = bg >> 5, g = bg & 31;
  const float* xp = x + (size_t)bg * 65536;
  float mean = stats[bg * 2 + 0] * (1.f / 65536.f);
  float var = stats[bg * 2 + 1] * (1.f / 65536.f) - mean * mean;
  float rstd = rsqrtf(var + 1e-6f);
  float wsc[16], bsc[16];
#pragma unroll
  for (int cc = 0; cc < 16; ++cc) {
    float wv = w[g * 16 + cc];
    wsc[cc] = wv * rstd;
    bsc[cc] = b[g * 16 + cc] - mean * wsc[cc];
  }
  u16* hp = ht + (size_t)batch * 4096 * 512 + g * 16;
  int t = threadIdx.x;
  for (int n = slice * 512 + t; n < slice * 512 + 512; n += 256) {
    union { u16 pk[16]; uint4 v4[2]; } u;
#pragma unroll
    for (int cc = 0; cc < 16; ++cc)
      u.pk[cc] = f2bf(xp[cc * 4096 + n] * wsc[cc] + bsc[cc]);
    uint4* dst = (uint4*)(hp + (size_t)n * 512);
    dst[0] = u.v4[0];
    dst[1] = u.v4[1];
  }
}

// ---------------- weight/bias fp32 -> bf16 ----------------
__global__ __launch_bounds__(256) void wcvt_kernel(
    const float* __restrict__ wq, const float* __restrict__ wk,
    const float* __restrict__ wv, const float* __restrict__ wo,
    const float* __restrict__ bq, const float* __restrict__ bk,
    u16* __restrict__ Wqk, u16* __restrict__ Wv, u16* __restrict__ Wo,
    float* __restrict__ Bqk) {
  int i = blockIdx.x * 256 + threadIdx.x;
  Wqk[i] = f2bf(wq[i]);
  Wqk[262144 + i] = f2bf(wk[i]);
  Wv[i] = f2bf(wv[i]);
  Wo[i] = f2bf(wo[i]);
  if (i < 512) { Bqk[i] = bq[i]; Bqk[512 + i] = bk[i]; }
}

// ---------------- TN MFMA GEMM, BM x 128 tile ----------------
// MODE 0: bf16 out, bias over n. MODE 1: bf16 out, bias over m.
// MODE 2: fp32 out at ((n>>12)*512+m)*4096+(n&4095), bias over m, +res.
template <int BM, int MODE>
__global__ __launch_bounds__(256) void mfma_gemm(
    const u16* __restrict__ A, int sA, const u16* __restrict__ B, int sB,
    const float* __restrict__ bias, const float* __restrict__ res,
    void* __restrict__ out, int ostr) {
  constexpr int TM = BM / 32;      // 16-tiles per wave in m
  constexpr int SIA = BM / 32;     // A staging rounds
  __shared__ char sm[BM * 128 + 16384];
  char* As = sm;                   // [kc8][mBM] 16B units
  char* Bs = sm + BM * 128;        // [kc8][n128]
  int t = threadIdx.x;
  int w = t >> 6, lane = t & 63, quad = lane >> 4, ln = lane & 15;
  int wm = w >> 1, wn = w & 1;
  int m0 = blockIdx.y * BM, n0 = blockIdx.x * 128;
  f32x4 acc[TM][4] = {};

  for (int k0 = 0; k0 < 512; k0 += 64) {
#pragma unroll
    for (int si = 0; si < SIA; ++si) {
      int s = (w * SIA + si) * 64 + lane;
      gll16(A + (size_t)(m0 + (s & (BM - 1))) * sA + k0 + (s >> (BM == 128 ? 7 : 6)) * 8,
            As + (w * SIA + si) * 1024);
    }
#pragma unroll
    for (int si = 0; si < 4; ++si) {
      int s = (w * 4 + si) * 64 + lane;
      gll16(B + (size_t)(n0 + (s & 127)) * sB + k0 + (s >> 7) * 8,
            Bs + (w * 4 + si) * 1024);
    }
    __syncthreads();
#pragma unroll
    for (int ks = 0; ks < 2; ++ks) {
      bf16x8 af[TM], bfr[4];
#pragma unroll
      for (int tm = 0; tm < TM; ++tm)
        af[tm] = *(const bf16x8*)(As + (((ks * 4 + quad) * BM) + wm * (BM / 2) + tm * 16 + ln) * 16);
#pragma unroll
      for (int tn = 0; tn < 4; ++tn)
        bfr[tn] = *(const bf16x8*)(Bs + (((ks * 4 + quad) * 128) + wn * 64 + tn * 16 + ln) * 16);
#pragma unroll
      for (int tm = 0; tm < TM; ++tm)
#pragma unroll
        for (int tn = 0; tn < 4; ++tn)
          acc[tm][tn] = __builtin_amdgcn_mfma_f32_16x16x32_bf16(af[tm], bfr[tn], acc[tm][tn], 0, 0, 0);
    }
    __syncthreads();
  }

#pragma unroll
  for (int tm = 0; tm < TM; ++tm) {
    int mb = m0 + wm * (BM / 2) + tm * 16 + quad * 4;
#pragma unroll
    for (int tn = 0; tn < 4; ++tn) {
      int n = n0 + wn * 64 + tn * 16 + ln;
      float bn = (MODE == 0) ? bias[n] : 0.f;
#pragma unroll
      for (int r = 0; r < 4; ++r) {
        int m = mb + r;
        float v = acc[tm][tn][r];
        if (MODE == 0) {
          ((u16*)out)[(size_t)m * ostr + n] = f2bf(v + bn);
        } else if (MODE == 1) {
          ((u16*)out)[(size_t)m * ostr + n] = f2bf(v + bias[m]);
        } else {
          int bb = n >> 12, nn = n & 4095;
          size_t off = ((size_t)(bb * 512 + m)) * 4096 + nn;
          ((float*)out)[off] = v + bias[m] + res[off];
        }
      }
    }
  }
}

// ---------------- flash attention, j-split 2-way ----------------
// Block: 512 thr (8 waves), BI=32 rows, j-half 2048, BJ=256/jblock.
// Per wave: S strip [32 i][32 j] (2x2), O strip [32 i][64 c] (2x4).
// LDS 53.6 KB -> 3 blocks/CU capacity; grid 512 -> 2 resident/CU.
__global__ __launch_bounds__(512) void flash_mfma(
    const u16* __restrict__ QKt, const u16* __restrict__ Vg,
    u16* __restrict__ Opart, float* __restrict__ ml) {
  __shared__ char smbuf[53632];
  char* Qs = smbuf;                        // 4 KB [kc8][i32] per cstep
  char* KVs = smbuf + 4096;                // 32 KB: K [kc8][j256] / V [kc4][c512]
  char* Ps = smbuf + 36864;                // 16 KB [kcj32][i32]
  float* rowm = (float*)(smbuf + 53248);
  float* rowa = rowm + 32;
  float* rowl = rowa + 32;
  float* smax = (float*)Qs;                // [8][32] alias (Qs dead at softmax)
  float* ssum = smax + 256;

  int t = threadIdx.x;
  int w = t >> 6, lane = t & 63, quad = lane >> 4, ln = lane & 15;
  int b = blockIdx.y, half = blockIdx.z;
  int i0 = blockIdx.x * 32;
  size_t prow0 = (size_t)b * 4096 + i0;

  if (t < 32) { rowm[t] = -1e30f; rowl[t] = 0.f; }
  f32x4 o[2][4] = {};  // i = tm*16+quad*4+r, c = w*64+tn*16+ln

  int qi = (w * 64 + lane) & 31, qkc = (w * 64 + lane) >> 5;
  __syncthreads();

  for (int j0 = half * 2048; j0 < half * 2048 + 2048; j0 += 256) {
    // ---- S = (Q K^T) * scale
    f32x4 sacc[2][2] = {};
    for (int cst = 0; cst < 8; ++cst) {
      if (w < 4)
        gll16(QKt + (prow0 + qi) * 1024 + cst * 64 + qkc * 8, Qs + w * 1024);
#pragma unroll
      for (int si = 0; si < 4; ++si) {
        int s = (w * 4 + si) * 64 + lane;
        gll16(QKt + ((size_t)b * 4096 + j0 + (s & 255)) * 1024 + 512 + cst * 64 + (s >> 8) * 8,
              KVs + (w * 4 + si) * 1024);
      }
      __syncthreads();
#pragma unroll
      for (int ks = 0; ks < 2; ++ks) {
        bf16x8 aq[2], bk_[2];
#pragma unroll
        for (int tm = 0; tm < 2; ++tm)
          aq[tm] = *(const bf16x8*)(Qs + (((ks * 4 + quad) * 32) + tm * 16 + ln) * 16);
#pragma unroll
        for (int tn = 0; tn < 2; ++tn)
          bk_[tn] = *(const bf16x8*)(KVs + (((ks * 4 + quad) * 256) + w * 32 + tn * 16 + ln) * 16);
#pragma unroll
        for (int tm = 0; tm < 2; ++tm)
#pragma unroll
          for (int tn = 0; tn < 2; ++tn)
            sacc[tm][tn] = __builtin_amdgcn_mfma_f32_16x16x32_bf16(aq[tm], bk_[tn], sacc[tm][tn], 0, 0, 0);
      }
      __syncthreads();
    }
#pragma unroll
    for (int tm = 0; tm < 2; ++tm)
#pragma unroll
      for (int tn = 0; tn < 2; ++tn)
#pragma unroll
        for (int r = 0; r < 4; ++r) sacc[tm][tn][r] *= 0.044194173824159216f;

    // ---- online softmax
    float mx[2][4];
#pragma unroll
    for (int tm = 0; tm < 2; ++tm)
#pragma unroll
      for (int r = 0; r < 4; ++r) {
        float m_ = fmaxf(sacc[tm][0][r], sacc[tm][1][r]);
#pragma unroll
        for (int d = 1; d < 16; d <<= 1) m_ = fmaxf(m_, __shfl_xor(m_, d));
        mx[tm][r] = m_;
      }
    if (ln == 0) {
#pragma unroll
      for (int tm = 0; tm < 2; ++tm)
#pragma unroll
        for (int r = 0; r < 4; ++r) smax[w * 32 + tm * 16 + quad * 4 + r] = mx[tm][r];
    }
    __syncthreads();
    if (t < 32) {
      float m_ = smax[t];
#pragma unroll
      for (int ww = 1; ww < 8; ++ww) m_ = fmaxf(m_, smax[ww * 32 + t]);
      float mold = rowm[t];
      float mnew = fmaxf(mold, m_);
      rowm[t] = mnew;
      rowa[t] = __expf(mold - mnew);
    }
    __syncthreads();
    float al[2][4];
#pragma unroll
    for (int tm = 0; tm < 2; ++tm)
#pragma unroll
      for (int r = 0; r < 4; ++r) {
        int i = tm * 16 + quad * 4 + r;
        float mrow = rowm[i];
        float sm_ = 0.f;
#pragma unroll
        for (int tn = 0; tn < 2; ++tn) {
          float p = __expf(sacc[tm][tn][r] - mrow);
          sm_ += p;
          int j = w * 32 + tn * 16 + ln;
          *(u16*)(Ps + ((j >> 3) * 32 + i) * 16 + (j & 7) * 2) = f2bf(p);
        }
#pragma unroll
        for (int d = 1; d < 16; d <<= 1) sm_ += __shfl_xor(sm_, d);
        if (ln == 0) ssum[w * 32 + i] = sm_;
        al[tm][r] = rowa[i];
      }
#pragma unroll
    for (int tm = 0; tm < 2; ++tm)
#pragma unroll
      for (int tn = 0; tn < 4; ++tn)
#pragma unroll
        for (int r = 0; r < 4; ++r) o[tm][tn][r] *= al[tm][r];
    __syncthreads();
    if (t < 32) {
      float a_ = 0.f;
#pragma unroll
      for (int ww = 0; ww < 8; ++ww) a_ += ssum[ww * 32 + t];
      rowl[t] = rowl[t] * rowa[t] + a_;
    }

    // ---- O += P V^T  (V chunks of 32 j x 512 c)
    for (int jh = 0; jh < 8; ++jh) {
#pragma unroll
      for (int si = 0; si < 4; ++si) {
        int s = (w * 4 + si) * 64 + lane;
        gll16(Vg + (size_t)(s & 511) * 8192 + (size_t)b * 4096 + j0 + jh * 32 + (s >> 9) * 8,
              KVs + (w * 4 + si) * 1024);
      }
      __syncthreads();
      bf16x8 ap[2], bv_[4];
#pragma unroll
      for (int tm = 0; tm < 2; ++tm)
        ap[tm] = *(const bf16x8*)(Ps + ((jh * 4 + quad) * 32 + tm * 16 + ln) * 16);
#pragma unroll
      for (int tn = 0; tn < 4; ++tn)
        bv_[tn] = *(const bf16x8*)(KVs + ((quad * 512) + w * 64 + tn * 16 + ln) * 16);
#pragma unroll
      for (int tm = 0; tm < 2; ++tm)
#pragma unroll
        for (int tn = 0; tn < 4; ++tn)
          o[tm][tn] = __builtin_amdgcn_mfma_f32_16x16x32_bf16(ap[tm], bv_[tn], o[tm][tn], 0, 0, 0);
      __syncthreads();
    }
  }

  // ---- write partials (un-normalized O, per-row m & l)
#pragma unroll
  for (int tm = 0; tm < 2; ++tm)
#pragma unroll
    for (int r = 0; r < 4; ++r) {
      int i = tm * 16 + quad * 4 + r;
      size_t row = prow0 + i;
#pragma unroll
      for (int tn = 0; tn < 4; ++tn) {
        int c = w * 64 + tn * 16 + ln;
        Opart[((size_t)half * 4096 * 2 + row) * 512 + c] = f2bf(o[tm][tn][r]);
      }
    }
  if (t < 32) {
    ml[(half * 2 + 0) * 8192 + prow0 + t] = rowm[t];
    ml[(half * 2 + 1) * 8192 + prow0 + t] = rowl[t];
  }
}

// ---------------- combine the two j-halves ----------------
__global__ __launch_bounds__(256) void combine_kernel(
    const u16* __restrict__ Opart, const float* __restrict__ ml,
    u16* __restrict__ AOt) {
  int id = blockIdx.x * 256 + threadIdx.x;   // 8192 * 128
  int row = id >> 7, cq = (id & 127) * 4;
  float m1 = ml[row], l1 = ml[8192 + row];
  float m2 = ml[16384 + row], l2 = ml[24576 + row];
  float M = fmaxf(m1, m2);
  float a1 = __expf(m1 - M), a2 = __expf(m2 - M);
  float inv = 1.f / (a1 * l1 + a2 * l2);
  ushort4 o1 = *(const ushort4*)(Opart + (size_t)row * 512 + cq);
  ushort4 o2 = *(const ushort4*)(Opart + (size_t)(8192 + row) * 512 + cq);
  ushort4 o;
  o.x = f2bf((a1 * bf2f(o1.x) + a2 * bf2f(o2.x)) * inv);
  o.y = f2bf((a1 * bf2f(o1.y) + a2 * bf2f(o2.y)) * inv);
  o.z = f2bf((a1 * bf2f(o1.z) + a2 * bf2f(o2.z)) * inv);
  o.w = f2bf((a1 * bf2f(o1.w) + a2 * bf2f(o2.w)) * inv);
  *(ushort4*)(AOt + (size_t)row * 512 + cq) = o;
}

// ---------------------------------------------------------------------------
extern "C" void kernel_launch(void* const* d_in, const int* in_sizes, int n_in,
                              void* d_out, int out_size, void* d_ws, size_t ws_size,
                              hipStream_t stream) {
  (void)in_sizes; (void)n_in; (void)out_size; (void)ws_size;
  const float* x = (const float*)d_in[0];
  const float* gnw = (const float*)d_in[1];
  const float* gnb = (const float*)d_in[2];
  const float* wq = (const float*)d_in[3];
  const float* bq = (const float*)d_in[4];
  const float* wk = (const float*)d_in[5];
  const float* bk = (const float*)d_in[6];
  const float* wv = (const float*)d_in[7];
  const float* bv = (const float*)d_in[8];
  const float* wo = (const float*)d_in[9];
  const float* bo = (const float*)d_in[10];
  float* out = (float*)d_out;

  char* ws = (char*)d_ws;
  u16* ht  = (u16*)(ws);
  u16* QKt = (u16*)(ws + 8388608);
  u16* Vg  = (u16*)(ws + 25165824);
  u16* AOt = (u16*)(ws + 33554432);
  u16* Wqk = (u16*)(ws + 41943040);
  u16* Wv  = (u16*)(ws + 42991616);
  u16* Wo  = (u16*)(ws + 43515904);
  float* Bqk   = (float*)(ws + 44040192);
  float* stats = (float*)(ws + 44044288);
  float* ml    = (float*)(ws + 44565504);
  u16* Opart   = (u16*)(ws + 45088768);

  wcvt_kernel<<<1024, 256, 0, stream>>>(wq, wk, wv, wo, bq, bk, Wqk, Wv, Wo, Bqk);
  zero_stats<<<1, 128, 0, stream>>>(stats);
  gn_stats<<<512, 256, 0, stream>>>(x, stats);
  gn_apply<<<512, 256, 0, stream>>>(x, gnw, gnb, stats, ht);
  // q|k = ht * Wqk^T -> [pix][1024]
  mfma_gemm<128, 0><<<dim3(8, 64), 256, 0, stream>>>(ht, 512, Wqk, 512, Bqk, nullptr, QKt, 1024);
  // v = Wv * ht^T -> [c][pix]
  mfma_gemm<64, 1><<<dim3(64, 8), 256, 0, stream>>>(Wv, 512, ht, 512, bv, nullptr, Vg, 8192);
  flash_mfma<<<dim3(128, 2, 2), 512, 0, stream>>>(QKt, Vg, Opart, ml);
  combine_kernel<<<4096, 256, 0, stream>>>(Opart, ml, AOt);
  // out = x + Wo * AO^T + bo -> fp32 [b][c][n]
  mfma_gemm<64, 2><<<dim3(64, 8), 256, 0, stream>>>(Wo, 512, AOt, 512, bo, x, out, 0);
}

// Round 4
// 415.072 us; speedup vs baseline: 1.4031x; 1.4031x over previous
//
#include <hip/hip_runtime.h>

// B=2, C=512, GROUPS=32, H=W=64, N=4096. Attention materialized per batch:
// S = (Q K^T)*scale GEMM -> exact row softmax (in place) -> O = P V^T GEMM.
// All GEMMs: m97 regime (256 thr, <=32 KB LDS, grid >= 512, global_load_lds w16).
//
// ws: ht/AOt[8192][512]@0 (8M) | QKt[8192][1024]@8M (16M) | S[4096][4096]@24M (32M)
//     Wqk@56M (1M) | Wv@57M (.5M) | Wo@57.5M (.5M)        -> 58 MB total
// d_out (16 MB, rewritten by final GEMM): Vg[512][8192]@0 (8M) | stats@8M | Bqk@8M+512

typedef __attribute__((ext_vector_type(8))) short bf16x8;
typedef __attribute__((ext_vector_type(4))) float f32x4;
typedef unsigned short u16;
typedef unsigned int u32;

__device__ __forceinline__ u16 f2bf(float f) {
  u32 u = __builtin_bit_cast(u32, f);
  return (u16)((u + 0x7FFFu + ((u >> 16) & 1u)) >> 16);
}
__device__ __forceinline__ float bf2f(u16 u) {
  return __builtin_bit_cast(float, (u32)u << 16);
}
__device__ __forceinline__ void gll16(const void* g, void* l) {
  __builtin_amdgcn_global_load_lds((const __attribute__((address_space(1))) u32*)g,
                                   (__attribute__((address_space(3))) u32*)l, 16, 0, 0);
}

// ---------------- GroupNorm: stats (atomic partial) + apply ----------------
__global__ void zero_stats(float* __restrict__ stats) {
  if (threadIdx.x < 128) stats[threadIdx.x] = 0.f;
}

__global__ __launch_bounds__(256) void gn_stats(const float* __restrict__ x,
                                                float* __restrict__ stats) {
  int bg = blockIdx.x >> 3, slice = blockIdx.x & 7;
  const float4* xp = (const float4*)(x + (size_t)bg * 65536 + slice * 8192);
  int t = threadIdx.x;
  float s = 0.f, ss = 0.f;
  for (int i = t; i < 2048; i += 256) {
    float4 v = xp[i];
    s += v.x + v.y + v.z + v.w;
    ss += v.x * v.x + v.y * v.y + v.z * v.z + v.w * v.w;
  }
  for (int off = 32; off > 0; off >>= 1) {
    s += __shfl_down(s, off);
    ss += __shfl_down(ss, off);
  }
  __shared__ float rs[4], rss[4];
  if ((t & 63) == 0) { rs[t >> 6] = s; rss[t >> 6] = ss; }
  __syncthreads();
  if (t == 0) {
    atomicAdd(&stats[bg * 2 + 0], rs[0] + rs[1] + rs[2] + rs[3]);
    atomicAdd(&stats[bg * 2 + 1], rss[0] + rss[1] + rss[2] + rss[3]);
  }
}

__global__ __launch_bounds__(256) void gn_apply(
    const float* __restrict__ x, const float* __restrict__ w,
    const float* __restrict__ b, const float* __restrict__ stats,
    u16* __restrict__ ht) {
  int bg = blockIdx.x >> 3, slice = blockIdx.x & 7;
  int batch = bg >> 5, g = bg & 31;
  const float* xp = x + (size_t)bg * 65536;
  float mean = stats[bg * 2 + 0] * (1.f / 65536.f);
  float var = stats[bg * 2 + 1] * (1.f / 65536.f) - mean * mean;
  float rstd = rsqrtf(var + 1e-6f);
  float wsc[16], bsc[16];
#pragma unroll
  for (int cc = 0; cc < 16; ++cc) {
    float wv = w[g * 16 + cc];
    wsc[cc] = wv * rstd;
    bsc[cc] = b[g * 16 + cc] - mean * wsc[cc];
  }
  u16* hp = ht + (size_t)batch * 4096 * 512 + g * 16;
  int t = threadIdx.x;
  for (int n = slice * 512 + t; n < slice * 512 + 512; n += 256) {
    union { u16 pk[16]; uint4 v4[2]; } u;
#pragma unroll
    for (int cc = 0; cc < 16; ++cc)
      u.pk[cc] = f2bf(xp[cc * 4096 + n] * wsc[cc] + bsc[cc]);
    uint4* dst = (uint4*)(hp + (size_t)n * 512);
    dst[0] = u.v4[0];
    dst[1] = u.v4[1];
  }
}

// ---------------- weight/bias fp32 -> bf16 ----------------
__global__ __launch_bounds__(256) void wcvt_kernel(
    const float* __restrict__ wq, const float* __restrict__ wk,
    const float* __restrict__ wv, const float* __restrict__ wo,
    const float* __restrict__ bq, const float* __restrict__ bk,
    u16* __restrict__ Wqk, u16* __restrict__ Wv, u16* __restrict__ Wo,
    float* __restrict__ Bqk) {
  int i = blockIdx.x * 256 + threadIdx.x;
  Wqk[i] = f2bf(wq[i]);
  Wqk[262144 + i] = f2bf(wk[i]);
  Wv[i] = f2bf(wv[i]);
  Wo[i] = f2bf(wo[i]);
  if (i < 512) { Bqk[i] = bq[i]; Bqk[512 + i] = bk[i]; }
}

// ---------------- TN MFMA GEMM, BM x BN tile, runtime K ----------------
// D[m][n] = sum_k A[m][k]*B[n][k]; 4 waves in 2x2; wave tile (BM/2)x(BN/2).
// MODE 0: bf16 out + bias[n]. MODE 1: bf16 out + bias[m].
// MODE 2: fp32 out at ((n>>12)*512+m)*4096+(n&4095) + bias[m] + res.
// MODE 3: bf16 out * scale. MODE 4: bf16 out.
template <int BM, int BN, int MODE>
__global__ __launch_bounds__(256) void mfma_gemm(
    const u16* __restrict__ A, int sA, const u16* __restrict__ B, int sB,
    int K, const float* __restrict__ bias, const float* __restrict__ res,
    void* __restrict__ out, int ostr, float scale) {
  constexpr int TM = BM / 32, TN = BN / 32;
  constexpr int SIA = BM / 32, SIB = BN / 32;  // 4 KB staging rounds
  __shared__ char sm[(BM + BN) * 128];
  char* As = sm;             // [kc8][mBM] 16B units
  char* Bs = sm + BM * 128;  // [kc8][nBN]
  int t = threadIdx.x;
  int w = t >> 6, lane = t & 63, quad = lane >> 4, ln = lane & 15;
  int wm = w >> 1, wn = w & 1;
  int m0 = blockIdx.y * BM, n0 = blockIdx.x * BN;
  f32x4 acc[TM][TN] = {};

  for (int k0 = 0; k0 < K; k0 += 64) {
#pragma unroll
    for (int si = 0; si < SIA; ++si) {
      int s = (w * SIA + si) * 64 + lane;
      gll16(A + (size_t)(m0 + (s & (BM - 1))) * sA + k0 + (s / BM) * 8,
            As + (w * SIA + si) * 1024);
    }
#pragma unroll
    for (int si = 0; si < SIB; ++si) {
      int s = (w * SIB + si) * 64 + lane;
      gll16(B + (size_t)(n0 + (s & (BN - 1))) * sB + k0 + (s / BN) * 8,
            Bs + (w * SIB + si) * 1024);
    }
    __syncthreads();
#pragma unroll
    for (int ks = 0; ks < 2; ++ks) {
      bf16x8 af[TM], bfr[TN];
#pragma unroll
      for (int tm = 0; tm < TM; ++tm)
        af[tm] = *(const bf16x8*)(As + (((ks * 4 + quad) * BM) + wm * (BM / 2) + tm * 16 + ln) * 16);
#pragma unroll
      for (int tn = 0; tn < TN; ++tn)
        bfr[tn] = *(const bf16x8*)(Bs + (((ks * 4 + quad) * BN) + wn * (BN / 2) + tn * 16 + ln) * 16);
#pragma unroll
      for (int tm = 0; tm < TM; ++tm)
#pragma unroll
        for (int tn = 0; tn < TN; ++tn)
          acc[tm][tn] = __builtin_amdgcn_mfma_f32_16x16x32_bf16(af[tm], bfr[tn], acc[tm][tn], 0, 0, 0);
    }
    __syncthreads();
  }

#pragma unroll
  for (int tm = 0; tm < TM; ++tm) {
    int mb = m0 + wm * (BM / 2) + tm * 16 + quad * 4;
#pragma unroll
    for (int tn = 0; tn < TN; ++tn) {
      int n = n0 + wn * (BN / 2) + tn * 16 + ln;
      float bn = (MODE == 0) ? bias[n] : 0.f;
#pragma unroll
      for (int r = 0; r < 4; ++r) {
        int m = mb + r;
        float v = acc[tm][tn][r];
        if (MODE == 0) {
          ((u16*)out)[(size_t)m * ostr + n] = f2bf(v + bn);
        } else if (MODE == 1) {
          ((u16*)out)[(size_t)m * ostr + n] = f2bf(v + bias[m]);
        } else if (MODE == 2) {
          int bb = n >> 12, nn = n & 4095;
          size_t off = ((size_t)(bb * 512 + m)) * 4096 + nn;
          ((float*)out)[off] = v + bias[m] + res[off];
        } else if (MODE == 3) {
          ((u16*)out)[(size_t)m * ostr + n] = f2bf(v * scale);
        } else {
          ((u16*)out)[(size_t)m * ostr + n] = f2bf(v);
        }
      }
    }
  }
}

// ---------------- exact row softmax, in place on S [rows][4096] bf16 --------
__global__ __launch_bounds__(256) void softmax_kernel(u16* __restrict__ S) {
  u16* sp = S + (size_t)blockIdx.x * 4096;
  int t = threadIdx.x;
  int w = t >> 6;
  uint4 a = ((const uint4*)sp)[t * 2];
  uint4 b = ((const uint4*)sp)[t * 2 + 1];
  u32 words[8] = {a.x, a.y, a.z, a.w, b.x, b.y, b.z, b.w};
  float v[16];
#pragma unroll
  for (int i = 0; i < 8; ++i) {
    v[2 * i] = bf2f((u16)(words[i] & 0xFFFF));
    v[2 * i + 1] = bf2f((u16)(words[i] >> 16));
  }
  float mx = v[0];
#pragma unroll
  for (int i = 1; i < 16; ++i) mx = fmaxf(mx, v[i]);
#pragma unroll
  for (int d = 1; d < 64; d <<= 1) mx = fmaxf(mx, __shfl_xor(mx, d));
  __shared__ float red[8];
  if ((t & 63) == 0) red[w] = mx;
  __syncthreads();
  mx = fmaxf(fmaxf(red[0], red[1]), fmaxf(red[2], red[3]));
  float sum = 0.f;
#pragma unroll
  for (int i = 0; i < 16; ++i) {
    v[i] = __expf(v[i] - mx);
    sum += v[i];
  }
#pragma unroll
  for (int d = 1; d < 64; d <<= 1) sum += __shfl_xor(sum, d);
  if ((t & 63) == 0) red[4 + w] = sum;
  __syncthreads();
  float inv = 1.f / (red[4] + red[5] + red[6] + red[7]);
#pragma unroll
  for (int i = 0; i < 8; ++i)
    words[i] = (u32)f2bf(v[2 * i] * inv) | ((u32)f2bf(v[2 * i + 1] * inv) << 16);
  ((uint4*)sp)[t * 2] = make_uint4(words[0], words[1], words[2], words[3]);
  ((uint4*)sp)[t * 2 + 1] = make_uint4(words[4], words[5], words[6], words[7]);
}

// ---------------------------------------------------------------------------
extern "C" void kernel_launch(void* const* d_in, const int* in_sizes, int n_in,
                              void* d_out, int out_size, void* d_ws, size_t ws_size,
                              hipStream_t stream) {
  (void)in_sizes; (void)n_in; (void)out_size; (void)ws_size;
  const float* x = (const float*)d_in[0];
  const float* gnw = (const float*)d_in[1];
  const float* gnb = (const float*)d_in[2];
  const float* wq = (const float*)d_in[3];
  const float* bq = (const float*)d_in[4];
  const float* wk = (const float*)d_in[5];
  const float* bk = (const float*)d_in[6];
  const float* wv = (const float*)d_in[7];
  const float* bv = (const float*)d_in[8];
  const float* wo = (const float*)d_in[9];
  const float* bo = (const float*)d_in[10];
  float* out = (float*)d_out;

  char* ws = (char*)d_ws;
  u16* ht  = (u16*)(ws);                  // 8 MB, aliased by AOt
  u16* AOt = (u16*)(ws);
  u16* QKt = (u16*)(ws + 8388608);        // 16 MB
  u16* S   = (u16*)(ws + 25165824);       // 32 MB (per batch)
  u16* Wqk = (u16*)(ws + 58720256);       // 1 MB
  u16* Wv  = (u16*)(ws + 59768832);       // 0.5 MB
  u16* Wo  = (u16*)(ws + 60293120);       // 0.5 MB
  // scratch inside d_out (dead before final GEMM rewrites it)
  u16* Vg      = (u16*)d_out;             // 8 MB [512][8192]
  float* stats = (float*)((char*)d_out + 8388608);
  float* Bqk   = (float*)((char*)d_out + 8389120);

  wcvt_kernel<<<1024, 256, 0, stream>>>(wq, wk, wv, wo, bq, bk, Wqk, Wv, Wo, Bqk);
  zero_stats<<<1, 128, 0, stream>>>(stats);
  gn_stats<<<512, 256, 0, stream>>>(x, stats);
  gn_apply<<<512, 256, 0, stream>>>(x, gnw, gnb, stats, ht);
  // q|k = ht * Wqk^T -> [pix][1024]
  mfma_gemm<128, 128, 0><<<dim3(8, 64), 256, 0, stream>>>(
      ht, 512, Wqk, 512, 512, Bqk, nullptr, QKt, 1024, 1.f);
  // v = Wv * ht^T -> Vg [c][pix] (in d_out)
  mfma_gemm<64, 128, 1><<<dim3(64, 8), 256, 0, stream>>>(
      Wv, 512, ht, 512, 512, bv, nullptr, Vg, 8192, 1.f);
  for (int b = 0; b < 2; ++b) {
    const u16* Qb = QKt + (size_t)b * 4096 * 1024;
    // S[i][j] = scale * sum_c q[i][c] k[j][c]
    mfma_gemm<128, 128, 3><<<dim3(32, 32), 256, 0, stream>>>(
        Qb, 1024, Qb + 512, 1024, 512, nullptr, nullptr, S, 4096,
        0.044194173824159216f);
    softmax_kernel<<<4096, 256, 0, stream>>>(S);
    // AO[i][c] = sum_j P[i][j] Vg[c][b*4096+j]
    mfma_gemm<64, 64, 4><<<dim3(8, 64), 256, 0, stream>>>(
        S, 4096, Vg + (size_t)b * 4096, 8192, 4096, nullptr, nullptr,
        AOt + (size_t)b * 4096 * 512, 512, 1.f);
  }
  // out = x + Wo * AO^T + bo -> fp32 [b][c][n]
  mfma_gemm<64, 128, 2><<<dim3(64, 8), 256, 0, stream>>>(
      Wo, 512, AOt, 512, 512, bo, x, out, 0, 1.f);
}